// Round 17
// baseline (148.692 us; speedup 1.0000x reference)
//
#include <hip/hip_runtime.h>
#include <hip/hip_bf16.h>
#include <cstdint>

// RoPE MHA fused pipeline, round 16: r15 + tail micro-trims: sigmoid folded
// into gemm8's G epilogue (Gb now holds sigmoid(g) bf16), attn prefetches the
// 8 gate words at kernel start -> attn tail is pure mul+store.
// B=2, L=2048, D=1024, H=16, HD=64.

constexpr int NB = 2, NL = 2048, ND = 1024, NH = 16, NHD = 64;
constexpr int NM = NB * NL; // 4096 tokens

typedef __bf16 bf16_t;
typedef __bf16 bf16x8 __attribute__((ext_vector_type(8)));
typedef __bf16 bf16x4 __attribute__((ext_vector_type(4)));
typedef float f32x4 __attribute__((ext_vector_type(4)));
typedef float f32x16 __attribute__((ext_vector_type(16)));
typedef unsigned int uint2v __attribute__((ext_vector_type(2)));

typedef const __attribute__((address_space(1))) void* gas_ptr;
typedef __attribute__((address_space(3))) void* las_ptr;

__device__ __forceinline__ void async_load16(const void* g, void* l) {
  __builtin_amdgcn_global_load_lds((gas_ptr)g, (las_ptr)l, 16, 0, 0);
}

__device__ __forceinline__ unsigned cvtpk_bf16(float lo, float hi) {
  unsigned r;
  asm("v_cvt_pk_bf16_f32 %0, %1, %2" : "=v"(r) : "v"(lo), "v"(hi));
  return r;
}

__device__ __forceinline__ void pl32_swap(unsigned& a, unsigned& b) {
#if __has_builtin(__builtin_amdgcn_permlane32_swap)
  uint2v r = __builtin_amdgcn_permlane32_swap(a, b, false, false);
  a = r.x; b = r.y;
#else
  asm volatile("v_permlane32_swap_b32 %0, %1" : "+v"(a), "+v"(b));
#endif
}

// raw v_exp_f32 (single trans-pipe instruction; 2^x)
__device__ __forceinline__ float fast_exp2(float x) {
#if __has_builtin(__builtin_amdgcn_exp2f)
  return __builtin_amdgcn_exp2f(x);
#else
  float r;
  asm("v_exp_f32 %0, %1" : "=v"(r) : "v"(x));
  return r;
#endif
}

// ---------------------------------------------------------------- conversion (fused)
// y<8: fp32->bf16 tensors. y==8: packed RoPE table PT[(l*16+lr)] = bf16x8
// {c[lr],c[16+lr],c[32+lr],c[48+lr], s[lr],s[16+lr],s[32+lr],s[48+lr]}.
struct CvtArgs {
  const float* s[8];
  bf16_t* d[8];
  const float* rc;
  const float* rs;
  bf16_t* pt;
};
__global__ __launch_bounds__(256) void cvt8_kernel(CvtArgs a) {
  int y = blockIdx.y;
  if (y == 8) {
    int n = NL * 16;
    for (int i = blockIdx.x * 256 + threadIdx.x; i < n; i += gridDim.x * 256) {
      int l = i >> 4, lr = i & 15;
      const float* c = a.rc + l * NHD + lr;
      const float* s = a.rs + l * NHD + lr;
      bf16x8 o;
      o[0] = (bf16_t)c[0];  o[1] = (bf16_t)c[16];
      o[2] = (bf16_t)c[32]; o[3] = (bf16_t)c[48];
      o[4] = (bf16_t)s[0];  o[5] = (bf16_t)s[16];
      o[6] = (bf16_t)s[32]; o[7] = (bf16_t)s[48];
      ((bf16x8*)a.pt)[i] = o;
    }
    return;
  }
  int n4 = (y < 3) ? (NM * ND / 4) : (ND * ND / 4);
  const float* src = a.s[y];
  bf16_t* dst = a.d[y];
  for (int i = blockIdx.x * 256 + threadIdx.x; i < n4; i += gridDim.x * 256) {
    float4 v = ((const float4*)src)[i];
    bf16x4 o;
    o[0] = (bf16_t)v.x; o[1] = (bf16_t)v.y; o[2] = (bf16_t)v.z; o[3] = (bf16_t)v.w;
    ((bf16x4*)dst)[i] = o;
  }
}

// ---------------------------------------------------------------- QKVG GEMM, 8-phase 256^2
__global__ __launch_bounds__(512, 2) void gemm8_kernel(
    const bf16_t* __restrict__ Aq, const bf16_t* __restrict__ Ak, const bf16_t* __restrict__ Av,
    const bf16_t* __restrict__ W0, const bf16_t* __restrict__ W1,
    const bf16_t* __restrict__ W2, const bf16_t* __restrict__ W3,
    const float* __restrict__ b0, const float* __restrict__ b1,
    const float* __restrict__ b2, const float* __restrict__ b3,
    const bf16_t* __restrict__ PT,
    bf16_t* __restrict__ Qr, bf16_t* __restrict__ Kr, bf16_t* __restrict__ Vt,
    bf16_t* __restrict__ Gb) {
  extern __shared__ __align__(16) bf16_t smem[];
  bf16_t* lA = smem;
  bf16_t* lB = smem + 32768;

  const int tid = threadIdx.x, lane = tid & 63, w = tid >> 6;
  const int wm = w >> 2, wn = w & 3;
  const int lr = lane & 15, lg = lane >> 4;

  const int lin = blockIdx.x;
  const int xcd = lin & 7, idx = lin >> 3;
  const int nt = xcd * 2 + (idx & 1);
  const int mt = idx >> 1;
  const int t = nt >> 2;
  const bf16_t* Asrc = (t == 1) ? Ak : (t == 2) ? Av : Aq;
  const bf16_t* Wsrc = (t == 0) ? W0 : (t == 1) ? W1 : (t == 2) ? W2 : W3;
  const int nbase = (nt & 3) * 256;

  const int srow = lane >> 3;
  const int gcol = ((lane & 7) ^ srow) * 8;

  auto stageA = [&](int buf, int hf, int kt) {
#pragma unroll
    for (int jj = 0; jj < 2; ++jj) {
      int slot = jj * 8 + w;
      int r = slot * 8 + srow;
      async_load16(Asrc + (size_t)(mt * 256 + hf * 128 + r) * ND + kt * 64 + gcol,
                   lA + (buf * 2 + hf) * 8192 + slot * 512);
    }
  };
  auto stageB = [&](int buf, int hf, int kt) {
#pragma unroll
    for (int jj = 0; jj < 2; ++jj) {
      int slot = jj * 8 + w;
      int r = slot * 8 + srow;
      async_load16(Wsrc + (size_t)(nbase + hf * 128 + r) * ND + kt * 64 + gcol,
                   lB + (buf * 2 + hf) * 8192 + slot * 512);
    }
  };

  f32x4 acc[8][4];
#pragma unroll
  for (int i = 0; i < 8; ++i)
#pragma unroll
    for (int j = 0; j < 4; ++j)
#pragma unroll
      for (int k = 0; k < 4; ++k) acc[i][j][k] = 0.f;

  stageA(0, 0, 0); stageA(0, 1, 0); stageB(0, 0, 0); stageB(0, 1, 0);
  stageB(1, 0, 1); stageB(1, 1, 1);
  asm volatile("s_waitcnt vmcnt(4)" ::: "memory");
  __builtin_amdgcn_s_barrier();

  const bf16_t* Ab[2] = { lA + wm * 8192, lA + (2 + wm) * 8192 };
  const bf16_t* Bb[2] = { lB + (wn >> 1) * 8192 + (wn & 1) * 4096,
                          lB + (2 + (wn >> 1)) * 8192 + (wn & 1) * 4096 };

  for (int j = 0; j < 8; ++j) {
#pragma unroll
    for (int hp = 0; hp < 2; ++hp) {
      const bf16_t* Ap = Ab[hp];
      const bf16_t* Bp = Bb[hp];
      bf16x8 bfr[4][2];
#pragma unroll
      for (int p = 0; p < 4; ++p) {
        bf16x8 af[2][2];
#pragma unroll
        for (int mi = 0; mi < 2; ++mi)
#pragma unroll
          for (int ks = 0; ks < 2; ++ks)
            af[mi][ks] = *(const bf16x8*)(Ap + ((p * 2 + mi) * 16 + lr) * 64 +
                                          ((ks * 4 + lg) ^ (lr & 7)) * 8);
        if (p == 0) {
#pragma unroll
          for (int nj = 0; nj < 4; ++nj)
#pragma unroll
            for (int ks = 0; ks < 2; ++ks)
              bfr[nj][ks] = *(const bf16x8*)(Bp + (nj * 16 + lr) * 64 +
                                             ((ks * 4 + lg) ^ (lr & 7)) * 8);
        }
        if (hp == 0) {
          if (p == 0) stageA(1, 0, 2 * j + 1);
          if (p == 1) { stageA(1, 1, 2 * j + 1); if (j < 7) stageB(0, 0, 2 * j + 2); }
          if (p == 2) { if (j < 7) stageB(0, 1, 2 * j + 2); }
        } else if (j < 7) {
          if (p == 0) stageA(0, 0, 2 * j + 2);
          if (p == 1) { stageA(0, 1, 2 * j + 2); stageB(1, 0, 2 * j + 3); }
          if (p == 2) stageB(1, 1, 2 * j + 3);
        }
        __builtin_amdgcn_s_barrier();
        __builtin_amdgcn_s_setprio(1);
#pragma unroll
        for (int mi = 0; mi < 2; ++mi)
#pragma unroll
          for (int nj = 0; nj < 4; ++nj)
#pragma unroll
            for (int ks = 0; ks < 2; ++ks)
              acc[p * 2 + mi][nj] = __builtin_amdgcn_mfma_f32_16x16x32_bf16(
                  af[mi][ks], bfr[nj][ks], acc[p * 2 + mi][nj], 0, 0, 0);
        __builtin_amdgcn_s_setprio(0);
        if (p == 3) {
          if (hp == 0) {
            if (j < 7) { asm volatile("s_waitcnt vmcnt(4)" ::: "memory"); }
            else       { asm volatile("s_waitcnt vmcnt(0)" ::: "memory"); }
          } else if (j < 7) {
            asm volatile("s_waitcnt vmcnt(4)" ::: "memory");
          }
        }
        __builtin_amdgcn_s_barrier();
      }
    }
  }

  const int fbase = nbase + wn * 64;
  const int h = fbase >> 6;
  if (t < 2) {
    bf16_t* dst = (t == 0) ? Qr : Kr;
    const float* bias = (t == 0) ? b0 : b1;
    const float qs = (t == 0) ? 0.18033688011112042f : 1.0f;  // 1/sqrt(64)*log2(e) into Q
    float bl[4];
#pragma unroll
    for (int d4 = 0; d4 < 4; ++d4) bl[d4] = bias[fbase + d4 * 16 + lr];
#pragma unroll
    for (int i = 0; i < 8; ++i)
#pragma unroll
      for (int rg = 0; rg < 4; ++rg) {
        int mm = mt * 256 + wm * 128 + i * 16 + lg * 4 + rg;
        int bb = mm >> 11, l = mm & (NL - 1);
        bf16_t* rowp = dst + ((bb * NH + h) * NL + l) * NHD;
        bf16x8 pk8 = *(const bf16x8*)(PT + (l * 16 + lr) * 8);  // one 16B load
#pragma unroll
        for (int nj = 0; nj < 2; ++nj) {
          int dlo = nj * 16 + lr, dhi = dlo + 32;
          float clo = (float)pk8[nj],     chi = (float)pk8[nj + 2];
          float slo = (float)pk8[nj + 4], shi = (float)pk8[nj + 6];
          float xlo = acc[i][nj][rg] + bl[nj];
          float xhi = acc[i][nj + 2][rg] + bl[nj + 2];
          rowp[dlo] = (bf16_t)((xlo * clo - xhi * slo) * qs);
          rowp[dhi] = (bf16_t)((xhi * chi + xlo * shi) * qs);
        }
      }
  } else if (t == 2) {
    float bl[4];
#pragma unroll
    for (int d4 = 0; d4 < 4; ++d4) bl[d4] = b2[fbase + d4 * 16 + lr];
#pragma unroll
    for (int i = 0; i < 8; ++i) {
      int mmb = mt * 256 + wm * 128 + i * 16 + lg * 4;
      int bb = mmb >> 11, l0 = mmb & (NL - 1);
#pragma unroll
      for (int nj = 0; nj < 4; ++nj) {
        int d = nj * 16 + lr;
        float bias = bl[nj];
        unsigned u01 = cvtpk_bf16(acc[i][nj][0] + bias, acc[i][nj][1] + bias);
        unsigned u23 = cvtpk_bf16(acc[i][nj][2] + bias, acc[i][nj][3] + bias);
        unsigned long long pk = (unsigned long long)u01 | ((unsigned long long)u23 << 32);
        *(unsigned long long*)(Vt + ((bb * NH + h) * NHD + d) * NL + l0) = pk;
      }
    }
  } else {
    // G: write sigmoid(g) directly (bf16) -- attn tail becomes pure mul
    float bl[4];
#pragma unroll
    for (int d4 = 0; d4 < 4; ++d4) bl[d4] = b3[fbase + d4 * 16 + lr];
#pragma unroll
    for (int i = 0; i < 8; ++i)
#pragma unroll
      for (int rg = 0; rg < 4; ++rg) {
        int mm = mt * 256 + wm * 128 + i * 16 + lg * 4 + rg;
#pragma unroll
        for (int nj = 0; nj < 4; ++nj) {
          int f = fbase + nj * 16 + lr;
          float g = acc[i][nj][rg] + bl[nj];
          float gate = 1.f / (1.f + fast_exp2(-1.44269504f * g));
          Gb[mm * ND + f] = (bf16_t)gate;
        }
      }
  }
}

// ---------------------------------------------------------------- out-projection GEMM (r4 structure)
__global__ __launch_bounds__(256) void gemm_out_kernel(
    const bf16_t* __restrict__ A, const bf16_t* __restrict__ W,
    const float* __restrict__ bias0, float* __restrict__ Out) {
  __shared__ __align__(16) bf16_t lA[2][128 * 64];
  __shared__ __align__(16) bf16_t lB[2][128 * 64];
  const int tid = threadIdx.x, lane = tid & 63, w = tid >> 6;
  const int wm = w >> 1, wn = w & 1;
  const int lr = lane & 15, lg = lane >> 4;

  const int lin = blockIdx.x;
  const int ntile = lin & 7, mtile = lin >> 3;

  const bf16_t* Ablk = A + mtile * 128 * ND;
  const bf16_t* Wblk = W + ntile * 128 * ND;

  f32x4 acc[4][4];
#pragma unroll
  for (int i = 0; i < 4; ++i)
#pragma unroll
    for (int j = 0; j < 4; ++j)
#pragma unroll
      for (int k = 0; k < 4; ++k) acc[i][j][k] = 0.f;

  auto STAGE = [&](int b, int kb) {
#pragma unroll
    for (int p = 0; p < 4; ++p) {
      int q = w * 256 + p * 64 + lane;
      int r = q >> 3, c = q & 7;
      int cs = c ^ (r & 7);
      async_load16(Ablk + r * ND + kb * 64 + cs * 8, &lA[b][(w * 256 + p * 64) * 8]);
      async_load16(Wblk + r * ND + kb * 64 + cs * 8, &lB[b][(w * 256 + p * 64) * 8]);
    }
  };
  auto COMPUTE = [&](int b) {
    const bf16_t* pA = lA[b];
    const bf16_t* pB = lB[b];
#pragma unroll
    for (int ks = 0; ks < 2; ++ks) {
      bf16x8 af[4], bfr[4];
#pragma unroll
      for (int i = 0; i < 4; ++i) {
        int ra = wm * 64 + i * 16 + lr;
        int ca = (ks * 4 + lg) ^ (ra & 7);
        af[i] = *(const bf16x8*)(pA + ra * 64 + ca * 8);
        int rb = wn * 64 + i * 16 + lr;
        int cb = (ks * 4 + lg) ^ (rb & 7);
        bfr[i] = *(const bf16x8*)(pB + rb * 64 + cb * 8);
      }
#pragma unroll
      for (int i = 0; i < 4; ++i)
#pragma unroll
        for (int j = 0; j < 4; ++j)
          acc[i][j] = __builtin_amdgcn_mfma_f32_16x16x32_bf16(af[i], bfr[j], acc[i][j], 0, 0, 0);
    }
  };

  STAGE(0, 0);
  __syncthreads();
  int buf = 0;
  for (int kb = 0; kb < 15; ++kb) {
    STAGE(buf ^ 1, kb + 1);
    COMPUTE(buf);
    __syncthreads();
    buf ^= 1;
  }
  COMPUTE(buf);

#pragma unroll
  for (int j = 0; j < 4; ++j) {
    int nn = ntile * 128 + wn * 64 + j * 16 + lr;
    float bias = bias0[nn];
#pragma unroll
    for (int i = 0; i < 4; ++i)
#pragma unroll
      for (int rg = 0; rg < 4; ++rg) {
        int mm = mtile * 128 + wm * 64 + i * 16 + lg * 4 + rg;
        Out[mm * ND + nn] = acc[i][j][rg] + bias;
      }
  }
}

// ---------------------------------------------------------------- flash attention (r11 + gate prefetch)
__global__ __launch_bounds__(256) void attn_kernel(
    const bf16_t* __restrict__ Qr, const bf16_t* __restrict__ Kr, const bf16_t* __restrict__ Vt,
    const int* __restrict__ mask, const bf16_t* __restrict__ Gb, bf16_t* __restrict__ X) {
  __shared__ __align__(16) bf16_t lK[2][128 * 64];
  __shared__ __align__(16) bf16_t lV[2][64 * 128];

  int lin = blockIdx.y * gridDim.x + blockIdx.x;
  int swz = (lin & 7) * 64 + (lin >> 3);
  const int qb = swz & 15, bh = swz >> 4;
  const int bb = bh >> 4, h = bh & 15;

  const int tid = threadIdx.x, lane = tid & 63, w = tid >> 6;
  const int ql = lane & 31, hi = lane >> 5;

  const bf16_t* Kbh = Kr + bh * NL * NHD;
  const bf16_t* Vbh = Vt + bh * NHD * NL;
  const int q = qb * 128 + w * 32 + ql;

  // Q fragments (B-operand, scale*log2e pre-folded)
  const bf16_t* Qp = Qr + (bh * NL + q) * NHD + 8 * hi;
  bf16x8 qf[4];
#pragma unroll
  for (int c = 0; c < 4; ++c) qf[c] = *(const bf16x8*)(Qp + 16 * c);
  bf16x8 qf5 = {};
  qf5[0] = (bf16_t)(hi ? 0.f : 1.f);

  // gate prefetch (Gb holds sigmoid already); values live in regs until tail
  const int rowbase = (bb * NL + q) * ND + h * NHD;
  bf16x4 gpre[8];
#pragma unroll
  for (int dt = 0; dt < 2; ++dt)
#pragma unroll
    for (int r1 = 0; r1 < 4; ++r1)
      gpre[dt * 4 + r1] = *(const bf16x4*)(Gb + rowbase + 32 * dt + 8 * r1 + 4 * hi);

  // loop-invariant constants kept in registers
  f32x16 zero16;
#pragma unroll
  for (int r = 0; r < 16; ++r) zero16[r] = 0.f;
  bf16x8 ones8;
#pragma unroll
  for (int r = 0; r < 8; ++r) ones8[r] = (bf16_t)1.f;

  f32x16 acc[2];
#pragma unroll
  for (int dt = 0; dt < 2; ++dt)
#pragma unroll
    for (int r = 0; r < 16; ++r) acc[dt][r] = 0.f;
  f32x16 lacc16 = zero16;   // l-partials; all 16 rows identical, col = lane's q

  // hoisted staging sources: 8 x 16B chunks per thread (K: j<4, V: j>=4)
  const bf16_t* gsrc[8];
#pragma unroll
  for (int j = 0; j < 8; ++j) {
    if (j < 4) {
      int u = j * 256 + tid;
      int r = u >> 3, c = u & 7, cs = c ^ (r & 7);
      gsrc[j] = Kbh + r * NHD + cs * 8;
    } else {
      int v = (j - 4) * 256 + tid;
      int r = v >> 4, c = v & 15, cs = (c & 8) | ((c & 7) ^ (r & 7));
      gsrc[j] = Vbh + r * NL + cs * 8;
    }
  }
  auto STAGE = [&](int b) {
#pragma unroll
    for (int j = 0; j < 8; ++j) {
      if (j < 4) {
        async_load16(gsrc[j], &lK[b][(j * 256 + tid) * 8]);
        gsrc[j] += 128 * NHD;
      } else {
        async_load16(gsrc[j], &lV[b][((j - 4) * 256 + tid) * 8]);
        gsrc[j] += 128;
      }
    }
  };

  // hoisted LDS read byte-offsets
  unsigned rdK[2][4], rdV[2][4];
#pragma unroll
  for (int t2 = 0; t2 < 2; ++t2)
#pragma unroll
    for (int c = 0; c < 4; ++c) {
      unsigned un = ((2 * c + hi) ^ (ql & 7)) * 16;
      rdK[t2][c] = (32 * t2 + ql) * 128 + un;
      rdV[t2][c] = (32 * t2 + ql) * 256 + un;
    }
  const char* lKc = (const char*)lK;
  const char* lVc = (const char*)lV;

  STAGE(0);
  int mv0 = mask[bb * NL + lane];
  int mv1 = mask[bb * NL + 64 + lane];
  __syncthreads();

  auto BODY = [&](int buf, int t) {
    int nmv0 = 0, nmv1 = 0;
    if (t < 15) {
      STAGE(buf ^ 1);
      nmv0 = mask[bb * NL + (t + 1) * 128 + lane];
      nmv1 = mask[bb * NL + (t + 1) * 128 + 64 + lane];
    }
    unsigned long long bmA = __ballot(mv0 != 0);
    unsigned long long bmB = __ballot(mv1 != 0);
    unsigned mws[4] = {(unsigned)bmA, (unsigned)(bmA >> 32),
                       (unsigned)bmB, (unsigned)(bmB >> 32)};
    bf16x8 kf5[4];
#pragma unroll
    for (int g = 0; g < 4; ++g) {
      float bv = ((mws[g] >> ql) & 1u) ? -1008.f : -8.f;
      bf16x8 z = {};
      z[0] = (bf16_t)(hi ? 0.f : bv);
      kf5[g] = z;
    }
#pragma unroll
    for (int hh = 0; hh < 2; ++hh) {
      // ---- S^T = K Q^T + bias: kf5 MFMA first with hoisted zero16 C-in
      f32x16 st[2];
      __builtin_amdgcn_s_setprio(1);
#pragma unroll
      for (int t2 = 0; t2 < 2; ++t2) {
        f32x16 s = __builtin_amdgcn_mfma_f32_32x32x16_bf16(kf5[hh * 2 + t2], qf5,
                                                           zero16, 0, 0, 0);
#pragma unroll
        for (int c = 0; c < 4; ++c) {
          bf16x8 kf = *(const bf16x8*)(lKc + rdK[t2][c] + buf * 16384 + hh * 8192);
          s = __builtin_amdgcn_mfma_f32_32x32x16_bf16(kf, qf[c], s, 0, 0, 0);
        }
        st[t2] = s;
      }
      __builtin_amdgcn_s_setprio(0);

      // ---- p = exp2(s - 8) via raw v_exp_f32; masked -> 2^-1005 = 0
#pragma unroll
      for (int t2 = 0; t2 < 2; ++t2)
#pragma unroll
        for (int r = 0; r < 16; ++r) st[t2][r] = fast_exp2(st[t2][r]);

      // ---- P -> bf16 B-operand fragments via cvt_pk + permlane32_swap
      unsigned wds[2][4][2];
#pragma unroll
      for (int t2 = 0; t2 < 2; ++t2)
#pragma unroll
        for (int r1 = 0; r1 < 4; ++r1) {
          wds[t2][r1][0] = cvtpk_bf16(st[t2][4 * r1 + 0], st[t2][4 * r1 + 1]);
          wds[t2][r1][1] = cvtpk_bf16(st[t2][4 * r1 + 2], st[t2][4 * r1 + 3]);
        }
      bf16x8 pf[4];
#pragma unroll
      for (int kc = 0; kc < 4; ++kc) {
        int t2 = kc >> 1, r1a = 2 * (kc & 1);
        unsigned a0 = wds[t2][r1a][0], b0 = wds[t2][r1a + 1][0];
        unsigned a1 = wds[t2][r1a][1], b1 = wds[t2][r1a + 1][1];
        pl32_swap(a0, b0);
        pl32_swap(a1, b1);
        union { unsigned u[4]; bf16x8 v; } uu;
        uu.u[0] = a0; uu.u[1] = a1; uu.u[2] = b0; uu.u[3] = b1;
        pf[kc] = uu.v;
      }

      // ---- acc^T[d][q] += V^T P^T ; l-partials on the matrix pipe (A = ones)
      __builtin_amdgcn_s_setprio(1);
#pragma unroll
      for (int dt = 0; dt < 2; ++dt) {
        f32x16 a = acc[dt];
#pragma unroll
        for (int kc = 0; kc < 4; ++kc) {
          bf16x8 vf = *(const bf16x8*)(lVc + rdV[dt][kc] + buf * 16384 + hh * 128);
          a = __builtin_amdgcn_mfma_f32_32x32x16_bf16(vf, pf[kc], a, 0, 0, 0);
        }
        acc[dt] = a;
      }
#pragma unroll
      for (int kc = 0; kc < 4; ++kc)
        lacc16 = __builtin_amdgcn_mfma_f32_32x32x16_bf16(ones8, pf[kc], lacc16, 0, 0, 0);
      __builtin_amdgcn_s_setprio(0);
    }
    __syncthreads();
    mv0 = nmv0;
    mv1 = nmv1;
  };

  for (int tt = 0; tt < 8; ++tt) {
    BODY(0, 2 * tt);
    BODY(1, 2 * tt + 1);
  }

  // ---- epilogue: l = lacc16[0]; gate already sigmoid (prefetched) -> pure mul
  float lt = lacc16[0];
  float rinv = lt > 0.f ? 1.f / lt : 0.f;
#pragma unroll
  for (int dt = 0; dt < 2; ++dt)
#pragma unroll
    for (int r1 = 0; r1 < 4; ++r1) {
      int dbase = 32 * dt + 8 * r1 + 4 * hi;
      bf16x4 g4 = gpre[dt * 4 + r1];
      bf16x4 o;
#pragma unroll
      for (int j = 0; j < 4; ++j)
        o[j] = (bf16_t)(acc[dt][4 * r1 + j] * rinv * (float)g4[j]);
      *(bf16x4*)(X + rowbase + dbase) = o;
    }
}

// ---------------------------------------------------------------- launch
extern "C" void kernel_launch(void* const* d_in, const int* in_sizes, int n_in,
                              void* d_out, int out_size, void* d_ws, size_t ws_size,
                              hipStream_t stream) {
  const float* query = (const float*)d_in[0];
  const float* key   = (const float*)d_in[1];
  const float* value = (const float*)d_in[2];
  const int*   maskp = (const int*)d_in[3];
  const float* rcos  = (const float*)d_in[4];
  const float* rsin  = (const float*)d_in[5];
  const float* Wq = (const float*)d_in[6];  const float* bq = (const float*)d_in[7];
  const float* Wk = (const float*)d_in[8];  const float* bk = (const float*)d_in[9];
  const float* Wv = (const float*)d_in[10]; const float* bv = (const float*)d_in[11];
  const float* Wg = (const float*)d_in[12]; const float* bg = (const float*)d_in[13];
  const float* Wo = (const float*)d_in[14]; const float* bo = (const float*)d_in[15];

  constexpr size_t MB = 1ull << 20;
  char* ws = (char*)d_ws;
  bf16_t* qbb = (bf16_t*)(ws + 0 * MB);
  bf16_t* kbb = (bf16_t*)(ws + 8 * MB);
  bf16_t* vbb = (bf16_t*)(ws + 16 * MB);
  bf16_t* wqb = (bf16_t*)(ws + 24 * MB);
  bf16_t* wkb = (bf16_t*)(ws + 26 * MB);
  bf16_t* wvb = (bf16_t*)(ws + 28 * MB);
  bf16_t* wgb = (bf16_t*)(ws + 30 * MB);
  bf16_t* wob = (bf16_t*)(ws + 32 * MB);
  bf16_t* Qr  = (bf16_t*)(ws + 34 * MB);
  bf16_t* Kr  = (bf16_t*)(ws + 42 * MB);
  bf16_t* Vt  = (bf16_t*)(ws + 50 * MB);
  bf16_t* Gb  = (bf16_t*)(ws + 58 * MB);
  bf16_t* PT  = (bf16_t*)(ws + 66 * MB);   // 512 KB packed rope table
  bf16_t* Xb  = (bf16_t*)(ws + 74 * MB);

  CvtArgs ca;
  ca.s[0] = query; ca.d[0] = qbb;
  ca.s[1] = key;   ca.d[1] = kbb;
  ca.s[2] = value; ca.d[2] = vbb;
  ca.s[3] = Wq;    ca.d[3] = wqb;
  ca.s[4] = Wk;    ca.d[4] = wkb;
  ca.s[5] = Wv;    ca.d[5] = wvb;
  ca.s[6] = Wg;    ca.d[6] = wgb;
  ca.s[7] = Wo;    ca.d[7] = wob;
  ca.rc = rcos; ca.rs = rsin; ca.pt = PT;
  cvt8_kernel<<<dim3(1024, 9), 256, 0, stream>>>(ca);

  gemm8_kernel<<<256, 512, 131072, stream>>>(
      qbb, kbb, vbb, wqb, wkb, wvb, wgb, bq, bk, bv, bg, PT,
      Qr, Kr, Vt, Gb);

  attn_kernel<<<dim3(16, 32), 256, 0, stream>>>(Qr, Kr, Vt, maskp, Gb, Xb);

  gemm_out_kernel<<<256, 256, 0, stream>>>(Xb, wob, bo, (float*)d_out);
}

// Round 18
// 133.301 us; speedup vs baseline: 1.1155x; 1.1155x over previous
//
#include <hip/hip_runtime.h>
#include <hip/hip_bf16.h>
#include <cstdint>

// RoPE MHA fused pipeline, round 17: r15 baseline + ONLY the sigmoid fold
// (gemm8 G-epilogue writes sigmoid(g) bf16; attn tail loads it and multiplies
// -- no prefetch-at-start, no gpre registers held across the loop; r16's
// scattered prefetch + register pressure regression reverted).
// B=2, L=2048, D=1024, H=16, HD=64.

constexpr int NB = 2, NL = 2048, ND = 1024, NH = 16, NHD = 64;
constexpr int NM = NB * NL; // 4096 tokens

typedef __bf16 bf16_t;
typedef __bf16 bf16x8 __attribute__((ext_vector_type(8)));
typedef __bf16 bf16x4 __attribute__((ext_vector_type(4)));
typedef float f32x4 __attribute__((ext_vector_type(4)));
typedef float f32x16 __attribute__((ext_vector_type(16)));
typedef unsigned int uint2v __attribute__((ext_vector_type(2)));

typedef const __attribute__((address_space(1))) void* gas_ptr;
typedef __attribute__((address_space(3))) void* las_ptr;

__device__ __forceinline__ void async_load16(const void* g, void* l) {
  __builtin_amdgcn_global_load_lds((gas_ptr)g, (las_ptr)l, 16, 0, 0);
}

__device__ __forceinline__ unsigned cvtpk_bf16(float lo, float hi) {
  unsigned r;
  asm("v_cvt_pk_bf16_f32 %0, %1, %2" : "=v"(r) : "v"(lo), "v"(hi));
  return r;
}

__device__ __forceinline__ void pl32_swap(unsigned& a, unsigned& b) {
#if __has_builtin(__builtin_amdgcn_permlane32_swap)
  uint2v r = __builtin_amdgcn_permlane32_swap(a, b, false, false);
  a = r.x; b = r.y;
#else
  asm volatile("v_permlane32_swap_b32 %0, %1" : "+v"(a), "+v"(b));
#endif
}

// raw v_exp_f32 (single trans-pipe instruction; 2^x)
__device__ __forceinline__ float fast_exp2(float x) {
#if __has_builtin(__builtin_amdgcn_exp2f)
  return __builtin_amdgcn_exp2f(x);
#else
  float r;
  asm("v_exp_f32 %0, %1" : "=v"(r) : "v"(x));
  return r;
#endif
}

// ---------------------------------------------------------------- conversion (fused)
// y<8: fp32->bf16 tensors. y==8: packed RoPE table PT[(l*16+lr)] = bf16x8
// {c[lr],c[16+lr],c[32+lr],c[48+lr], s[lr],s[16+lr],s[32+lr],s[48+lr]}.
struct CvtArgs {
  const float* s[8];
  bf16_t* d[8];
  const float* rc;
  const float* rs;
  bf16_t* pt;
};
__global__ __launch_bounds__(256) void cvt8_kernel(CvtArgs a) {
  int y = blockIdx.y;
  if (y == 8) {
    int n = NL * 16;
    for (int i = blockIdx.x * 256 + threadIdx.x; i < n; i += gridDim.x * 256) {
      int l = i >> 4, lr = i & 15;
      const float* c = a.rc + l * NHD + lr;
      const float* s = a.rs + l * NHD + lr;
      bf16x8 o;
      o[0] = (bf16_t)c[0];  o[1] = (bf16_t)c[16];
      o[2] = (bf16_t)c[32]; o[3] = (bf16_t)c[48];
      o[4] = (bf16_t)s[0];  o[5] = (bf16_t)s[16];
      o[6] = (bf16_t)s[32]; o[7] = (bf16_t)s[48];
      ((bf16x8*)a.pt)[i] = o;
    }
    return;
  }
  int n4 = (y < 3) ? (NM * ND / 4) : (ND * ND / 4);
  const float* src = a.s[y];
  bf16_t* dst = a.d[y];
  for (int i = blockIdx.x * 256 + threadIdx.x; i < n4; i += gridDim.x * 256) {
    float4 v = ((const float4*)src)[i];
    bf16x4 o;
    o[0] = (bf16_t)v.x; o[1] = (bf16_t)v.y; o[2] = (bf16_t)v.z; o[3] = (bf16_t)v.w;
    ((bf16x4*)dst)[i] = o;
  }
}

// ---------------------------------------------------------------- QKVG GEMM, 8-phase 256^2
__global__ __launch_bounds__(512, 2) void gemm8_kernel(
    const bf16_t* __restrict__ Aq, const bf16_t* __restrict__ Ak, const bf16_t* __restrict__ Av,
    const bf16_t* __restrict__ W0, const bf16_t* __restrict__ W1,
    const bf16_t* __restrict__ W2, const bf16_t* __restrict__ W3,
    const float* __restrict__ b0, const float* __restrict__ b1,
    const float* __restrict__ b2, const float* __restrict__ b3,
    const bf16_t* __restrict__ PT,
    bf16_t* __restrict__ Qr, bf16_t* __restrict__ Kr, bf16_t* __restrict__ Vt,
    bf16_t* __restrict__ Gb) {
  extern __shared__ __align__(16) bf16_t smem[];
  bf16_t* lA = smem;
  bf16_t* lB = smem + 32768;

  const int tid = threadIdx.x, lane = tid & 63, w = tid >> 6;
  const int wm = w >> 2, wn = w & 3;
  const int lr = lane & 15, lg = lane >> 4;

  const int lin = blockIdx.x;
  const int xcd = lin & 7, idx = lin >> 3;
  const int nt = xcd * 2 + (idx & 1);
  const int mt = idx >> 1;
  const int t = nt >> 2;
  const bf16_t* Asrc = (t == 1) ? Ak : (t == 2) ? Av : Aq;
  const bf16_t* Wsrc = (t == 0) ? W0 : (t == 1) ? W1 : (t == 2) ? W2 : W3;
  const int nbase = (nt & 3) * 256;

  const int srow = lane >> 3;
  const int gcol = ((lane & 7) ^ srow) * 8;

  auto stageA = [&](int buf, int hf, int kt) {
#pragma unroll
    for (int jj = 0; jj < 2; ++jj) {
      int slot = jj * 8 + w;
      int r = slot * 8 + srow;
      async_load16(Asrc + (size_t)(mt * 256 + hf * 128 + r) * ND + kt * 64 + gcol,
                   lA + (buf * 2 + hf) * 8192 + slot * 512);
    }
  };
  auto stageB = [&](int buf, int hf, int kt) {
#pragma unroll
    for (int jj = 0; jj < 2; ++jj) {
      int slot = jj * 8 + w;
      int r = slot * 8 + srow;
      async_load16(Wsrc + (size_t)(nbase + hf * 128 + r) * ND + kt * 64 + gcol,
                   lB + (buf * 2 + hf) * 8192 + slot * 512);
    }
  };

  f32x4 acc[8][4];
#pragma unroll
  for (int i = 0; i < 8; ++i)
#pragma unroll
    for (int j = 0; j < 4; ++j)
#pragma unroll
      for (int k = 0; k < 4; ++k) acc[i][j][k] = 0.f;

  stageA(0, 0, 0); stageA(0, 1, 0); stageB(0, 0, 0); stageB(0, 1, 0);
  stageB(1, 0, 1); stageB(1, 1, 1);
  asm volatile("s_waitcnt vmcnt(4)" ::: "memory");
  __builtin_amdgcn_s_barrier();

  const bf16_t* Ab[2] = { lA + wm * 8192, lA + (2 + wm) * 8192 };
  const bf16_t* Bb[2] = { lB + (wn >> 1) * 8192 + (wn & 1) * 4096,
                          lB + (2 + (wn >> 1)) * 8192 + (wn & 1) * 4096 };

  for (int j = 0; j < 8; ++j) {
#pragma unroll
    for (int hp = 0; hp < 2; ++hp) {
      const bf16_t* Ap = Ab[hp];
      const bf16_t* Bp = Bb[hp];
      bf16x8 bfr[4][2];
#pragma unroll
      for (int p = 0; p < 4; ++p) {
        bf16x8 af[2][2];
#pragma unroll
        for (int mi = 0; mi < 2; ++mi)
#pragma unroll
          for (int ks = 0; ks < 2; ++ks)
            af[mi][ks] = *(const bf16x8*)(Ap + ((p * 2 + mi) * 16 + lr) * 64 +
                                          ((ks * 4 + lg) ^ (lr & 7)) * 8);
        if (p == 0) {
#pragma unroll
          for (int nj = 0; nj < 4; ++nj)
#pragma unroll
            for (int ks = 0; ks < 2; ++ks)
              bfr[nj][ks] = *(const bf16x8*)(Bp + (nj * 16 + lr) * 64 +
                                             ((ks * 4 + lg) ^ (lr & 7)) * 8);
        }
        if (hp == 0) {
          if (p == 0) stageA(1, 0, 2 * j + 1);
          if (p == 1) { stageA(1, 1, 2 * j + 1); if (j < 7) stageB(0, 0, 2 * j + 2); }
          if (p == 2) { if (j < 7) stageB(0, 1, 2 * j + 2); }
        } else if (j < 7) {
          if (p == 0) stageA(0, 0, 2 * j + 2);
          if (p == 1) { stageA(0, 1, 2 * j + 2); stageB(1, 0, 2 * j + 3); }
          if (p == 2) stageB(1, 1, 2 * j + 3);
        }
        __builtin_amdgcn_s_barrier();
        __builtin_amdgcn_s_setprio(1);
#pragma unroll
        for (int mi = 0; mi < 2; ++mi)
#pragma unroll
          for (int nj = 0; nj < 4; ++nj)
#pragma unroll
            for (int ks = 0; ks < 2; ++ks)
              acc[p * 2 + mi][nj] = __builtin_amdgcn_mfma_f32_16x16x32_bf16(
                  af[mi][ks], bfr[nj][ks], acc[p * 2 + mi][nj], 0, 0, 0);
        __builtin_amdgcn_s_setprio(0);
        if (p == 3) {
          if (hp == 0) {
            if (j < 7) { asm volatile("s_waitcnt vmcnt(4)" ::: "memory"); }
            else       { asm volatile("s_waitcnt vmcnt(0)" ::: "memory"); }
          } else if (j < 7) {
            asm volatile("s_waitcnt vmcnt(4)" ::: "memory");
          }
        }
        __builtin_amdgcn_s_barrier();
      }
    }
  }

  const int fbase = nbase + wn * 64;
  const int h = fbase >> 6;
  if (t < 2) {
    bf16_t* dst = (t == 0) ? Qr : Kr;
    const float* bias = (t == 0) ? b0 : b1;
    const float qs = (t == 0) ? 0.18033688011112042f : 1.0f;  // 1/sqrt(64)*log2(e) into Q
    float bl[4];
#pragma unroll
    for (int d4 = 0; d4 < 4; ++d4) bl[d4] = bias[fbase + d4 * 16 + lr];
#pragma unroll
    for (int i = 0; i < 8; ++i)
#pragma unroll
      for (int rg = 0; rg < 4; ++rg) {
        int mm = mt * 256 + wm * 128 + i * 16 + lg * 4 + rg;
        int bb = mm >> 11, l = mm & (NL - 1);
        bf16_t* rowp = dst + ((bb * NH + h) * NL + l) * NHD;
        bf16x8 pk8 = *(const bf16x8*)(PT + (l * 16 + lr) * 8);  // one 16B load
#pragma unroll
        for (int nj = 0; nj < 2; ++nj) {
          int dlo = nj * 16 + lr, dhi = dlo + 32;
          float clo = (float)pk8[nj],     chi = (float)pk8[nj + 2];
          float slo = (float)pk8[nj + 4], shi = (float)pk8[nj + 6];
          float xlo = acc[i][nj][rg] + bl[nj];
          float xhi = acc[i][nj + 2][rg] + bl[nj + 2];
          rowp[dlo] = (bf16_t)((xlo * clo - xhi * slo) * qs);
          rowp[dhi] = (bf16_t)((xhi * chi + xlo * shi) * qs);
        }
      }
  } else if (t == 2) {
    float bl[4];
#pragma unroll
    for (int d4 = 0; d4 < 4; ++d4) bl[d4] = b2[fbase + d4 * 16 + lr];
#pragma unroll
    for (int i = 0; i < 8; ++i) {
      int mmb = mt * 256 + wm * 128 + i * 16 + lg * 4;
      int bb = mmb >> 11, l0 = mmb & (NL - 1);
#pragma unroll
      for (int nj = 0; nj < 4; ++nj) {
        int d = nj * 16 + lr;
        float bias = bl[nj];
        unsigned u01 = cvtpk_bf16(acc[i][nj][0] + bias, acc[i][nj][1] + bias);
        unsigned u23 = cvtpk_bf16(acc[i][nj][2] + bias, acc[i][nj][3] + bias);
        unsigned long long pk = (unsigned long long)u01 | ((unsigned long long)u23 << 32);
        *(unsigned long long*)(Vt + ((bb * NH + h) * NHD + d) * NL + l0) = pk;
      }
    }
  } else {
    // G: write sigmoid(g) directly (bf16) -- attn tail becomes load+mul
    float bl[4];
#pragma unroll
    for (int d4 = 0; d4 < 4; ++d4) bl[d4] = b3[fbase + d4 * 16 + lr];
#pragma unroll
    for (int i = 0; i < 8; ++i)
#pragma unroll
      for (int rg = 0; rg < 4; ++rg) {
        int mm = mt * 256 + wm * 128 + i * 16 + lg * 4 + rg;
#pragma unroll
        for (int nj = 0; nj < 4; ++nj) {
          int f = fbase + nj * 16 + lr;
          float g = acc[i][nj][rg] + bl[nj];
          float gate = 1.f / (1.f + fast_exp2(-1.44269504f * g));
          Gb[mm * ND + f] = (bf16_t)gate;
        }
      }
  }
}

// ---------------------------------------------------------------- out-projection GEMM (r4 structure)
__global__ __launch_bounds__(256) void gemm_out_kernel(
    const bf16_t* __restrict__ A, const bf16_t* __restrict__ W,
    const float* __restrict__ bias0, float* __restrict__ Out) {
  __shared__ __align__(16) bf16_t lA[2][128 * 64];
  __shared__ __align__(16) bf16_t lB[2][128 * 64];
  const int tid = threadIdx.x, lane = tid & 63, w = tid >> 6;
  const int wm = w >> 1, wn = w & 1;
  const int lr = lane & 15, lg = lane >> 4;

  const int lin = blockIdx.x;
  const int ntile = lin & 7, mtile = lin >> 3;

  const bf16_t* Ablk = A + mtile * 128 * ND;
  const bf16_t* Wblk = W + ntile * 128 * ND;

  f32x4 acc[4][4];
#pragma unroll
  for (int i = 0; i < 4; ++i)
#pragma unroll
    for (int j = 0; j < 4; ++j)
#pragma unroll
      for (int k = 0; k < 4; ++k) acc[i][j][k] = 0.f;

  auto STAGE = [&](int b, int kb) {
#pragma unroll
    for (int p = 0; p < 4; ++p) {
      int q = w * 256 + p * 64 + lane;
      int r = q >> 3, c = q & 7;
      int cs = c ^ (r & 7);
      async_load16(Ablk + r * ND + kb * 64 + cs * 8, &lA[b][(w * 256 + p * 64) * 8]);
      async_load16(Wblk + r * ND + kb * 64 + cs * 8, &lB[b][(w * 256 + p * 64) * 8]);
    }
  };
  auto COMPUTE = [&](int b) {
    const bf16_t* pA = lA[b];
    const bf16_t* pB = lB[b];
#pragma unroll
    for (int ks = 0; ks < 2; ++ks) {
      bf16x8 af[4], bfr[4];
#pragma unroll
      for (int i = 0; i < 4; ++i) {
        int ra = wm * 64 + i * 16 + lr;
        int ca = (ks * 4 + lg) ^ (ra & 7);
        af[i] = *(const bf16x8*)(pA + ra * 64 + ca * 8);
        int rb = wn * 64 + i * 16 + lr;
        int cb = (ks * 4 + lg) ^ (rb & 7);
        bfr[i] = *(const bf16x8*)(pB + rb * 64 + cb * 8);
      }
#pragma unroll
      for (int i = 0; i < 4; ++i)
#pragma unroll
        for (int j = 0; j < 4; ++j)
          acc[i][j] = __builtin_amdgcn_mfma_f32_16x16x32_bf16(af[i], bfr[j], acc[i][j], 0, 0, 0);
    }
  };

  STAGE(0, 0);
  __syncthreads();
  int buf = 0;
  for (int kb = 0; kb < 15; ++kb) {
    STAGE(buf ^ 1, kb + 1);
    COMPUTE(buf);
    __syncthreads();
    buf ^= 1;
  }
  COMPUTE(buf);

#pragma unroll
  for (int j = 0; j < 4; ++j) {
    int nn = ntile * 128 + wn * 64 + j * 16 + lr;
    float bias = bias0[nn];
#pragma unroll
    for (int i = 0; i < 4; ++i)
#pragma unroll
      for (int rg = 0; rg < 4; ++rg) {
        int mm = mtile * 128 + wm * 64 + i * 16 + lg * 4 + rg;
        Out[mm * ND + nn] = acc[i][j][rg] + bias;
      }
  }
}

// ---------------------------------------------------------------- flash attention (r15 + sigmoid-free tail)
__global__ __launch_bounds__(256) void attn_kernel(
    const bf16_t* __restrict__ Qr, const bf16_t* __restrict__ Kr, const bf16_t* __restrict__ Vt,
    const int* __restrict__ mask, const bf16_t* __restrict__ Gb, bf16_t* __restrict__ X) {
  __shared__ __align__(16) bf16_t lK[2][128 * 64];
  __shared__ __align__(16) bf16_t lV[2][64 * 128];

  int lin = blockIdx.y * gridDim.x + blockIdx.x;
  int swz = (lin & 7) * 64 + (lin >> 3);
  const int qb = swz & 15, bh = swz >> 4;
  const int bb = bh >> 4, h = bh & 15;

  const int tid = threadIdx.x, lane = tid & 63, w = tid >> 6;
  const int ql = lane & 31, hi = lane >> 5;

  const bf16_t* Kbh = Kr + bh * NL * NHD;
  const bf16_t* Vbh = Vt + bh * NHD * NL;
  const int q = qb * 128 + w * 32 + ql;

  // Q fragments (B-operand, scale*log2e pre-folded)
  const bf16_t* Qp = Qr + (bh * NL + q) * NHD + 8 * hi;
  bf16x8 qf[4];
#pragma unroll
  for (int c = 0; c < 4; ++c) qf[c] = *(const bf16x8*)(Qp + 16 * c);
  bf16x8 qf5 = {};
  qf5[0] = (bf16_t)(hi ? 0.f : 1.f);

  // loop-invariant constants kept in registers
  f32x16 zero16;
#pragma unroll
  for (int r = 0; r < 16; ++r) zero16[r] = 0.f;
  bf16x8 ones8;
#pragma unroll
  for (int r = 0; r < 8; ++r) ones8[r] = (bf16_t)1.f;

  f32x16 acc[2];
#pragma unroll
  for (int dt = 0; dt < 2; ++dt)
#pragma unroll
    for (int r = 0; r < 16; ++r) acc[dt][r] = 0.f;
  f32x16 lacc16 = zero16;   // l-partials; all 16 rows identical, col = lane's q

  // hoisted staging sources: 8 x 16B chunks per thread (K: j<4, V: j>=4)
  const bf16_t* gsrc[8];
#pragma unroll
  for (int j = 0; j < 8; ++j) {
    if (j < 4) {
      int u = j * 256 + tid;
      int r = u >> 3, c = u & 7, cs = c ^ (r & 7);
      gsrc[j] = Kbh + r * NHD + cs * 8;
    } else {
      int v = (j - 4) * 256 + tid;
      int r = v >> 4, c = v & 15, cs = (c & 8) | ((c & 7) ^ (r & 7));
      gsrc[j] = Vbh + r * NL + cs * 8;
    }
  }
  auto STAGE = [&](int b) {
#pragma unroll
    for (int j = 0; j < 8; ++j) {
      if (j < 4) {
        async_load16(gsrc[j], &lK[b][(j * 256 + tid) * 8]);
        gsrc[j] += 128 * NHD;
      } else {
        async_load16(gsrc[j], &lV[b][((j - 4) * 256 + tid) * 8]);
        gsrc[j] += 128;
      }
    }
  };

  // hoisted LDS read byte-offsets
  unsigned rdK[2][4], rdV[2][4];
#pragma unroll
  for (int t2 = 0; t2 < 2; ++t2)
#pragma unroll
    for (int c = 0; c < 4; ++c) {
      unsigned un = ((2 * c + hi) ^ (ql & 7)) * 16;
      rdK[t2][c] = (32 * t2 + ql) * 128 + un;
      rdV[t2][c] = (32 * t2 + ql) * 256 + un;
    }
  const char* lKc = (const char*)lK;
  const char* lVc = (const char*)lV;

  STAGE(0);
  int mv0 = mask[bb * NL + lane];
  int mv1 = mask[bb * NL + 64 + lane];
  __syncthreads();

  auto BODY = [&](int buf, int t) {
    int nmv0 = 0, nmv1 = 0;
    if (t < 15) {
      STAGE(buf ^ 1);
      nmv0 = mask[bb * NL + (t + 1) * 128 + lane];
      nmv1 = mask[bb * NL + (t + 1) * 128 + 64 + lane];
    }
    unsigned long long bmA = __ballot(mv0 != 0);
    unsigned long long bmB = __ballot(mv1 != 0);
    unsigned mws[4] = {(unsigned)bmA, (unsigned)(bmA >> 32),
                       (unsigned)bmB, (unsigned)(bmB >> 32)};
    bf16x8 kf5[4];
#pragma unroll
    for (int g = 0; g < 4; ++g) {
      float bv = ((mws[g] >> ql) & 1u) ? -1008.f : -8.f;
      bf16x8 z = {};
      z[0] = (bf16_t)(hi ? 0.f : bv);
      kf5[g] = z;
    }
#pragma unroll
    for (int hh = 0; hh < 2; ++hh) {
      // ---- S^T = K Q^T + bias: kf5 MFMA first with hoisted zero16 C-in
      f32x16 st[2];
      __builtin_amdgcn_s_setprio(1);
#pragma unroll
      for (int t2 = 0; t2 < 2; ++t2) {
        f32x16 s = __builtin_amdgcn_mfma_f32_32x32x16_bf16(kf5[hh * 2 + t2], qf5,
                                                           zero16, 0, 0, 0);
#pragma unroll
        for (int c = 0; c < 4; ++c) {
          bf16x8 kf = *(const bf16x8*)(lKc + rdK[t2][c] + buf * 16384 + hh * 8192);
          s = __builtin_amdgcn_mfma_f32_32x32x16_bf16(kf, qf[c], s, 0, 0, 0);
        }
        st[t2] = s;
      }
      __builtin_amdgcn_s_setprio(0);

      // ---- p = exp2(s - 8) via raw v_exp_f32; masked -> 2^-1005 = 0
#pragma unroll
      for (int t2 = 0; t2 < 2; ++t2)
#pragma unroll
        for (int r = 0; r < 16; ++r) st[t2][r] = fast_exp2(st[t2][r]);

      // ---- P -> bf16 B-operand fragments via cvt_pk + permlane32_swap
      unsigned wds[2][4][2];
#pragma unroll
      for (int t2 = 0; t2 < 2; ++t2)
#pragma unroll
        for (int r1 = 0; r1 < 4; ++r1) {
          wds[t2][r1][0] = cvtpk_bf16(st[t2][4 * r1 + 0], st[t2][4 * r1 + 1]);
          wds[t2][r1][1] = cvtpk_bf16(st[t2][4 * r1 + 2], st[t2][4 * r1 + 3]);
        }
      bf16x8 pf[4];
#pragma unroll
      for (int kc = 0; kc < 4; ++kc) {
        int t2 = kc >> 1, r1a = 2 * (kc & 1);
        unsigned a0 = wds[t2][r1a][0], b0 = wds[t2][r1a + 1][0];
        unsigned a1 = wds[t2][r1a][1], b1 = wds[t2][r1a + 1][1];
        pl32_swap(a0, b0);
        pl32_swap(a1, b1);
        union { unsigned u[4]; bf16x8 v; } uu;
        uu.u[0] = a0; uu.u[1] = a1; uu.u[2] = b0; uu.u[3] = b1;
        pf[kc] = uu.v;
      }

      // ---- acc^T[d][q] += V^T P^T ; l-partials on the matrix pipe (A = ones)
      __builtin_amdgcn_s_setprio(1);
#pragma unroll
      for (int dt = 0; dt < 2; ++dt) {
        f32x16 a = acc[dt];
#pragma unroll
        for (int kc = 0; kc < 4; ++kc) {
          bf16x8 vf = *(const bf16x8*)(lVc + rdV[dt][kc] + buf * 16384 + hh * 128);
          a = __builtin_amdgcn_mfma_f32_32x32x16_bf16(vf, pf[kc], a, 0, 0, 0);
        }
        acc[dt] = a;
      }
#pragma unroll
      for (int kc = 0; kc < 4; ++kc)
        lacc16 = __builtin_amdgcn_mfma_f32_32x32x16_bf16(ones8, pf[kc], lacc16, 0, 0, 0);
      __builtin_amdgcn_s_setprio(0);
    }
    __syncthreads();
    mv0 = nmv0;
    mv1 = nmv1;
  };

  for (int tt = 0; tt < 8; ++tt) {
    BODY(0, 2 * tt);
    BODY(1, 2 * tt + 1);
  }

  // ---- epilogue: l = lacc16[0]; Gb already sigmoid -> load + mul only
  float lt = lacc16[0];
  float rinv = lt > 0.f ? 1.f / lt : 0.f;
  const int rowbase = (bb * NL + q) * ND + h * NHD;
#pragma unroll
  for (int dt = 0; dt < 2; ++dt)
#pragma unroll
    for (int r1 = 0; r1 < 4; ++r1) {
      int dbase = 32 * dt + 8 * r1 + 4 * hi;
      bf16x4 g4 = *(const bf16x4*)(Gb + rowbase + dbase);
      bf16x4 o;
#pragma unroll
      for (int j = 0; j < 4; ++j)
        o[j] = (bf16_t)(acc[dt][4 * r1 + j] * rinv * (float)g4[j]);
      *(bf16x4*)(X + rowbase + dbase) = o;
    }
}

// ---------------------------------------------------------------- launch
extern "C" void kernel_launch(void* const* d_in, const int* in_sizes, int n_in,
                              void* d_out, int out_size, void* d_ws, size_t ws_size,
                              hipStream_t stream) {
  const float* query = (const float*)d_in[0];
  const float* key   = (const float*)d_in[1];
  const float* value = (const float*)d_in[2];
  const int*   maskp = (const int*)d_in[3];
  const float* rcos  = (const float*)d_in[4];
  const float* rsin  = (const float*)d_in[5];
  const float* Wq = (const float*)d_in[6];  const float* bq = (const float*)d_in[7];
  const float* Wk = (const float*)d_in[8];  const float* bk = (const float*)d_in[9];
  const float* Wv = (const float*)d_in[10]; const float* bv = (const float*)d_in[11];
  const float* Wg = (const float*)d_in[12]; const float* bg = (const float*)d_in[13];
  const float* Wo = (const float*)d_in[14]; const float* bo = (const float*)d_in[15];

  constexpr size_t MB = 1ull << 20;
  char* ws = (char*)d_ws;
  bf16_t* qbb = (bf16_t*)(ws + 0 * MB);
  bf16_t* kbb = (bf16_t*)(ws + 8 * MB);
  bf16_t* vbb = (bf16_t*)(ws + 16 * MB);
  bf16_t* wqb = (bf16_t*)(ws + 24 * MB);
  bf16_t* wkb = (bf16_t*)(ws + 26 * MB);
  bf16_t* wvb = (bf16_t*)(ws + 28 * MB);
  bf16_t* wgb = (bf16_t*)(ws + 30 * MB);
  bf16_t* wob = (bf16_t*)(ws + 32 * MB);
  bf16_t* Qr  = (bf16_t*)(ws + 34 * MB);
  bf16_t* Kr  = (bf16_t*)(ws + 42 * MB);
  bf16_t* Vt  = (bf16_t*)(ws + 50 * MB);
  bf16_t* Gb  = (bf16_t*)(ws + 58 * MB);
  bf16_t* PT  = (bf16_t*)(ws + 66 * MB);   // 512 KB packed rope table
  bf16_t* Xb  = (bf16_t*)(ws + 74 * MB);

  CvtArgs ca;
  ca.s[0] = query; ca.d[0] = qbb;
  ca.s[1] = key;   ca.d[1] = kbb;
  ca.s[2] = value; ca.d[2] = vbb;
  ca.s[3] = Wq;    ca.d[3] = wqb;
  ca.s[4] = Wk;    ca.d[4] = wkb;
  ca.s[5] = Wv;    ca.d[5] = wvb;
  ca.s[6] = Wg;    ca.d[6] = wgb;
  ca.s[7] = Wo;    ca.d[7] = wob;
  ca.rc = rcos; ca.rs = rsin; ca.pt = PT;
  cvt8_kernel<<<dim3(1024, 9), 256, 0, stream>>>(ca);

  gemm8_kernel<<<256, 512, 131072, stream>>>(
      qbb, kbb, vbb, wqb, wkb, wvb, wgb, bq, bk, bv, bg, PT,
      Qr, Kr, Vt, Gb);

  attn_kernel<<<dim3(16, 32), 256, 0, stream>>>(Qr, Kr, Vt, maskp, Gb, Xb);

  gemm_out_kernel<<<256, 256, 0, stream>>>(Xb, wob, bo, (float*)d_out);
}

// Round 19
// 128.205 us; speedup vs baseline: 1.1598x; 1.0398x over previous
//
#include <hip/hip_runtime.h>
#include <hip/hip_bf16.h>
#include <cstdint>

// RoPE MHA fused pipeline, round 18: r15 baseline (131.5us best) with ONE
// change: s_setprio pairs removed from attn BODY. Theory: the setprio
// intrinsics are code-motion fences serializing the two independent 64-key
// half-streams; removing them lets the scheduler interleave QK(h1) with
// softmax/PV(h0) (VGPR headroom is free at 2 waves/SIMD).
// B=2, L=2048, D=1024, H=16, HD=64.

constexpr int NB = 2, NL = 2048, ND = 1024, NH = 16, NHD = 64;
constexpr int NM = NB * NL; // 4096 tokens

typedef __bf16 bf16_t;
typedef __bf16 bf16x8 __attribute__((ext_vector_type(8)));
typedef __bf16 bf16x4 __attribute__((ext_vector_type(4)));
typedef float f32x4 __attribute__((ext_vector_type(4)));
typedef float f32x16 __attribute__((ext_vector_type(16)));
typedef unsigned int uint2v __attribute__((ext_vector_type(2)));

typedef const __attribute__((address_space(1))) void* gas_ptr;
typedef __attribute__((address_space(3))) void* las_ptr;

__device__ __forceinline__ void async_load16(const void* g, void* l) {
  __builtin_amdgcn_global_load_lds((gas_ptr)g, (las_ptr)l, 16, 0, 0);
}

__device__ __forceinline__ unsigned cvtpk_bf16(float lo, float hi) {
  unsigned r;
  asm("v_cvt_pk_bf16_f32 %0, %1, %2" : "=v"(r) : "v"(lo), "v"(hi));
  return r;
}

__device__ __forceinline__ void pl32_swap(unsigned& a, unsigned& b) {
#if __has_builtin(__builtin_amdgcn_permlane32_swap)
  uint2v r = __builtin_amdgcn_permlane32_swap(a, b, false, false);
  a = r.x; b = r.y;
#else
  asm volatile("v_permlane32_swap_b32 %0, %1" : "+v"(a), "+v"(b));
#endif
}

// raw v_exp_f32 (single trans-pipe instruction; 2^x)
__device__ __forceinline__ float fast_exp2(float x) {
#if __has_builtin(__builtin_amdgcn_exp2f)
  return __builtin_amdgcn_exp2f(x);
#else
  float r;
  asm("v_exp_f32 %0, %1" : "=v"(r) : "v"(x));
  return r;
#endif
}

// ---------------------------------------------------------------- conversion (fused)
// y<8: fp32->bf16 tensors. y==8: packed RoPE table PT[(l*16+lr)] = bf16x8
// {c[lr],c[16+lr],c[32+lr],c[48+lr], s[lr],s[16+lr],s[32+lr],s[48+lr]}.
struct CvtArgs {
  const float* s[8];
  bf16_t* d[8];
  const float* rc;
  const float* rs;
  bf16_t* pt;
};
__global__ __launch_bounds__(256) void cvt8_kernel(CvtArgs a) {
  int y = blockIdx.y;
  if (y == 8) {
    int n = NL * 16;
    for (int i = blockIdx.x * 256 + threadIdx.x; i < n; i += gridDim.x * 256) {
      int l = i >> 4, lr = i & 15;
      const float* c = a.rc + l * NHD + lr;
      const float* s = a.rs + l * NHD + lr;
      bf16x8 o;
      o[0] = (bf16_t)c[0];  o[1] = (bf16_t)c[16];
      o[2] = (bf16_t)c[32]; o[3] = (bf16_t)c[48];
      o[4] = (bf16_t)s[0];  o[5] = (bf16_t)s[16];
      o[6] = (bf16_t)s[32]; o[7] = (bf16_t)s[48];
      ((bf16x8*)a.pt)[i] = o;
    }
    return;
  }
  int n4 = (y < 3) ? (NM * ND / 4) : (ND * ND / 4);
  const float* src = a.s[y];
  bf16_t* dst = a.d[y];
  for (int i = blockIdx.x * 256 + threadIdx.x; i < n4; i += gridDim.x * 256) {
    float4 v = ((const float4*)src)[i];
    bf16x4 o;
    o[0] = (bf16_t)v.x; o[1] = (bf16_t)v.y; o[2] = (bf16_t)v.z; o[3] = (bf16_t)v.w;
    ((bf16x4*)dst)[i] = o;
  }
}

// ---------------------------------------------------------------- QKVG GEMM, 8-phase 256^2
__global__ __launch_bounds__(512, 2) void gemm8_kernel(
    const bf16_t* __restrict__ Aq, const bf16_t* __restrict__ Ak, const bf16_t* __restrict__ Av,
    const bf16_t* __restrict__ W0, const bf16_t* __restrict__ W1,
    const bf16_t* __restrict__ W2, const bf16_t* __restrict__ W3,
    const float* __restrict__ b0, const float* __restrict__ b1,
    const float* __restrict__ b2, const float* __restrict__ b3,
    const bf16_t* __restrict__ PT,
    bf16_t* __restrict__ Qr, bf16_t* __restrict__ Kr, bf16_t* __restrict__ Vt,
    bf16_t* __restrict__ Gb) {
  extern __shared__ __align__(16) bf16_t smem[];
  bf16_t* lA = smem;
  bf16_t* lB = smem + 32768;

  const int tid = threadIdx.x, lane = tid & 63, w = tid >> 6;
  const int wm = w >> 2, wn = w & 3;
  const int lr = lane & 15, lg = lane >> 4;

  const int lin = blockIdx.x;
  const int xcd = lin & 7, idx = lin >> 3;
  const int nt = xcd * 2 + (idx & 1);
  const int mt = idx >> 1;
  const int t = nt >> 2;
  const bf16_t* Asrc = (t == 1) ? Ak : (t == 2) ? Av : Aq;
  const bf16_t* Wsrc = (t == 0) ? W0 : (t == 1) ? W1 : (t == 2) ? W2 : W3;
  const int nbase = (nt & 3) * 256;

  const int srow = lane >> 3;
  const int gcol = ((lane & 7) ^ srow) * 8;

  auto stageA = [&](int buf, int hf, int kt) {
#pragma unroll
    for (int jj = 0; jj < 2; ++jj) {
      int slot = jj * 8 + w;
      int r = slot * 8 + srow;
      async_load16(Asrc + (size_t)(mt * 256 + hf * 128 + r) * ND + kt * 64 + gcol,
                   lA + (buf * 2 + hf) * 8192 + slot * 512);
    }
  };
  auto stageB = [&](int buf, int hf, int kt) {
#pragma unroll
    for (int jj = 0; jj < 2; ++jj) {
      int slot = jj * 8 + w;
      int r = slot * 8 + srow;
      async_load16(Wsrc + (size_t)(nbase + hf * 128 + r) * ND + kt * 64 + gcol,
                   lB + (buf * 2 + hf) * 8192 + slot * 512);
    }
  };

  f32x4 acc[8][4];
#pragma unroll
  for (int i = 0; i < 8; ++i)
#pragma unroll
    for (int j = 0; j < 4; ++j)
#pragma unroll
      for (int k = 0; k < 4; ++k) acc[i][j][k] = 0.f;

  stageA(0, 0, 0); stageA(0, 1, 0); stageB(0, 0, 0); stageB(0, 1, 0);
  stageB(1, 0, 1); stageB(1, 1, 1);
  asm volatile("s_waitcnt vmcnt(4)" ::: "memory");
  __builtin_amdgcn_s_barrier();

  const bf16_t* Ab[2] = { lA + wm * 8192, lA + (2 + wm) * 8192 };
  const bf16_t* Bb[2] = { lB + (wn >> 1) * 8192 + (wn & 1) * 4096,
                          lB + (2 + (wn >> 1)) * 8192 + (wn & 1) * 4096 };

  for (int j = 0; j < 8; ++j) {
#pragma unroll
    for (int hp = 0; hp < 2; ++hp) {
      const bf16_t* Ap = Ab[hp];
      const bf16_t* Bp = Bb[hp];
      bf16x8 bfr[4][2];
#pragma unroll
      for (int p = 0; p < 4; ++p) {
        bf16x8 af[2][2];
#pragma unroll
        for (int mi = 0; mi < 2; ++mi)
#pragma unroll
          for (int ks = 0; ks < 2; ++ks)
            af[mi][ks] = *(const bf16x8*)(Ap + ((p * 2 + mi) * 16 + lr) * 64 +
                                          ((ks * 4 + lg) ^ (lr & 7)) * 8);
        if (p == 0) {
#pragma unroll
          for (int nj = 0; nj < 4; ++nj)
#pragma unroll
            for (int ks = 0; ks < 2; ++ks)
              bfr[nj][ks] = *(const bf16x8*)(Bp + (nj * 16 + lr) * 64 +
                                             ((ks * 4 + lg) ^ (lr & 7)) * 8);
        }
        if (hp == 0) {
          if (p == 0) stageA(1, 0, 2 * j + 1);
          if (p == 1) { stageA(1, 1, 2 * j + 1); if (j < 7) stageB(0, 0, 2 * j + 2); }
          if (p == 2) { if (j < 7) stageB(0, 1, 2 * j + 2); }
        } else if (j < 7) {
          if (p == 0) stageA(0, 0, 2 * j + 2);
          if (p == 1) { stageA(0, 1, 2 * j + 2); stageB(1, 0, 2 * j + 3); }
          if (p == 2) stageB(1, 1, 2 * j + 3);
        }
        __builtin_amdgcn_s_barrier();
        __builtin_amdgcn_s_setprio(1);
#pragma unroll
        for (int mi = 0; mi < 2; ++mi)
#pragma unroll
          for (int nj = 0; nj < 4; ++nj)
#pragma unroll
            for (int ks = 0; ks < 2; ++ks)
              acc[p * 2 + mi][nj] = __builtin_amdgcn_mfma_f32_16x16x32_bf16(
                  af[mi][ks], bfr[nj][ks], acc[p * 2 + mi][nj], 0, 0, 0);
        __builtin_amdgcn_s_setprio(0);
        if (p == 3) {
          if (hp == 0) {
            if (j < 7) { asm volatile("s_waitcnt vmcnt(4)" ::: "memory"); }
            else       { asm volatile("s_waitcnt vmcnt(0)" ::: "memory"); }
          } else if (j < 7) {
            asm volatile("s_waitcnt vmcnt(4)" ::: "memory");
          }
        }
        __builtin_amdgcn_s_barrier();
      }
    }
  }

  const int fbase = nbase + wn * 64;
  const int h = fbase >> 6;
  if (t < 2) {
    bf16_t* dst = (t == 0) ? Qr : Kr;
    const float* bias = (t == 0) ? b0 : b1;
    const float qs = (t == 0) ? 0.18033688011112042f : 1.0f;  // 1/sqrt(64)*log2(e) into Q
    float bl[4];
#pragma unroll
    for (int d4 = 0; d4 < 4; ++d4) bl[d4] = bias[fbase + d4 * 16 + lr];
#pragma unroll
    for (int i = 0; i < 8; ++i)
#pragma unroll
      for (int rg = 0; rg < 4; ++rg) {
        int mm = mt * 256 + wm * 128 + i * 16 + lg * 4 + rg;
        int bb = mm >> 11, l = mm & (NL - 1);
        bf16_t* rowp = dst + ((bb * NH + h) * NL + l) * NHD;
        bf16x8 pk8 = *(const bf16x8*)(PT + (l * 16 + lr) * 8);  // one 16B load
#pragma unroll
        for (int nj = 0; nj < 2; ++nj) {
          int dlo = nj * 16 + lr, dhi = dlo + 32;
          float clo = (float)pk8[nj],     chi = (float)pk8[nj + 2];
          float slo = (float)pk8[nj + 4], shi = (float)pk8[nj + 6];
          float xlo = acc[i][nj][rg] + bl[nj];
          float xhi = acc[i][nj + 2][rg] + bl[nj + 2];
          rowp[dlo] = (bf16_t)((xlo * clo - xhi * slo) * qs);
          rowp[dhi] = (bf16_t)((xhi * chi + xlo * shi) * qs);
        }
      }
  } else if (t == 2) {
    float bl[4];
#pragma unroll
    for (int d4 = 0; d4 < 4; ++d4) bl[d4] = b2[fbase + d4 * 16 + lr];
#pragma unroll
    for (int i = 0; i < 8; ++i) {
      int mmb = mt * 256 + wm * 128 + i * 16 + lg * 4;
      int bb = mmb >> 11, l0 = mmb & (NL - 1);
#pragma unroll
      for (int nj = 0; nj < 4; ++nj) {
        int d = nj * 16 + lr;
        float bias = bl[nj];
        unsigned u01 = cvtpk_bf16(acc[i][nj][0] + bias, acc[i][nj][1] + bias);
        unsigned u23 = cvtpk_bf16(acc[i][nj][2] + bias, acc[i][nj][3] + bias);
        unsigned long long pk = (unsigned long long)u01 | ((unsigned long long)u23 << 32);
        *(unsigned long long*)(Vt + ((bb * NH + h) * NHD + d) * NL + l0) = pk;
      }
    }
  } else {
    float bl[4];
#pragma unroll
    for (int d4 = 0; d4 < 4; ++d4) bl[d4] = b3[fbase + d4 * 16 + lr];
#pragma unroll
    for (int i = 0; i < 8; ++i)
#pragma unroll
      for (int rg = 0; rg < 4; ++rg) {
        int mm = mt * 256 + wm * 128 + i * 16 + lg * 4 + rg;
#pragma unroll
        for (int nj = 0; nj < 4; ++nj) {
          int f = fbase + nj * 16 + lr;
          Gb[mm * ND + f] = (bf16_t)(acc[i][nj][rg] + bl[nj]);
        }
      }
  }
}

// ---------------------------------------------------------------- out-projection GEMM (r4 structure)
__global__ __launch_bounds__(256) void gemm_out_kernel(
    const bf16_t* __restrict__ A, const bf16_t* __restrict__ W,
    const float* __restrict__ bias0, float* __restrict__ Out) {
  __shared__ __align__(16) bf16_t lA[2][128 * 64];
  __shared__ __align__(16) bf16_t lB[2][128 * 64];
  const int tid = threadIdx.x, lane = tid & 63, w = tid >> 6;
  const int wm = w >> 1, wn = w & 1;
  const int lr = lane & 15, lg = lane >> 4;

  const int lin = blockIdx.x;
  const int ntile = lin & 7, mtile = lin >> 3;

  const bf16_t* Ablk = A + mtile * 128 * ND;
  const bf16_t* Wblk = W + ntile * 128 * ND;

  f32x4 acc[4][4];
#pragma unroll
  for (int i = 0; i < 4; ++i)
#pragma unroll
    for (int j = 0; j < 4; ++j)
#pragma unroll
      for (int k = 0; k < 4; ++k) acc[i][j][k] = 0.f;

  auto STAGE = [&](int b, int kb) {
#pragma unroll
    for (int p = 0; p < 4; ++p) {
      int q = w * 256 + p * 64 + lane;
      int r = q >> 3, c = q & 7;
      int cs = c ^ (r & 7);
      async_load16(Ablk + r * ND + kb * 64 + cs * 8, &lA[b][(w * 256 + p * 64) * 8]);
      async_load16(Wblk + r * ND + kb * 64 + cs * 8, &lB[b][(w * 256 + p * 64) * 8]);
    }
  };
  auto COMPUTE = [&](int b) {
    const bf16_t* pA = lA[b];
    const bf16_t* pB = lB[b];
#pragma unroll
    for (int ks = 0; ks < 2; ++ks) {
      bf16x8 af[4], bfr[4];
#pragma unroll
      for (int i = 0; i < 4; ++i) {
        int ra = wm * 64 + i * 16 + lr;
        int ca = (ks * 4 + lg) ^ (ra & 7);
        af[i] = *(const bf16x8*)(pA + ra * 64 + ca * 8);
        int rb = wn * 64 + i * 16 + lr;
        int cb = (ks * 4 + lg) ^ (rb & 7);
        bfr[i] = *(const bf16x8*)(pB + rb * 64 + cb * 8);
      }
#pragma unroll
      for (int i = 0; i < 4; ++i)
#pragma unroll
        for (int j = 0; j < 4; ++j)
          acc[i][j] = __builtin_amdgcn_mfma_f32_16x16x32_bf16(af[i], bfr[j], acc[i][j], 0, 0, 0);
    }
  };

  STAGE(0, 0);
  __syncthreads();
  int buf = 0;
  for (int kb = 0; kb < 15; ++kb) {
    STAGE(buf ^ 1, kb + 1);
    COMPUTE(buf);
    __syncthreads();
    buf ^= 1;
  }
  COMPUTE(buf);

#pragma unroll
  for (int j = 0; j < 4; ++j) {
    int nn = ntile * 128 + wn * 64 + j * 16 + lr;
    float bias = bias0[nn];
#pragma unroll
    for (int i = 0; i < 4; ++i)
#pragma unroll
      for (int rg = 0; rg < 4; ++rg) {
        int mm = mtile * 128 + wm * 64 + i * 16 + lg * 4 + rg;
        Out[mm * ND + nn] = acc[i][j][rg] + bias;
      }
  }
}

// ---------------------------------------------------------------- flash attention (r15, setprio removed)
__global__ __launch_bounds__(256) void attn_kernel(
    const bf16_t* __restrict__ Qr, const bf16_t* __restrict__ Kr, const bf16_t* __restrict__ Vt,
    const int* __restrict__ mask, const bf16_t* __restrict__ Gb, bf16_t* __restrict__ X) {
  __shared__ __align__(16) bf16_t lK[2][128 * 64];
  __shared__ __align__(16) bf16_t lV[2][64 * 128];

  int lin = blockIdx.y * gridDim.x + blockIdx.x;
  int swz = (lin & 7) * 64 + (lin >> 3);
  const int qb = swz & 15, bh = swz >> 4;
  const int bb = bh >> 4, h = bh & 15;

  const int tid = threadIdx.x, lane = tid & 63, w = tid >> 6;
  const int ql = lane & 31, hi = lane >> 5;

  const bf16_t* Kbh = Kr + bh * NL * NHD;
  const bf16_t* Vbh = Vt + bh * NHD * NL;
  const int q = qb * 128 + w * 32 + ql;

  // Q fragments (B-operand, scale*log2e pre-folded)
  const bf16_t* Qp = Qr + (bh * NL + q) * NHD + 8 * hi;
  bf16x8 qf[4];
#pragma unroll
  for (int c = 0; c < 4; ++c) qf[c] = *(const bf16x8*)(Qp + 16 * c);
  bf16x8 qf5 = {};
  qf5[0] = (bf16_t)(hi ? 0.f : 1.f);

  // loop-invariant constants kept in registers
  f32x16 zero16;
#pragma unroll
  for (int r = 0; r < 16; ++r) zero16[r] = 0.f;
  bf16x8 ones8;
#pragma unroll
  for (int r = 0; r < 8; ++r) ones8[r] = (bf16_t)1.f;

  f32x16 acc[2];
#pragma unroll
  for (int dt = 0; dt < 2; ++dt)
#pragma unroll
    for (int r = 0; r < 16; ++r) acc[dt][r] = 0.f;
  f32x16 lacc16 = zero16;   // l-partials; all 16 rows identical, col = lane's q

  // hoisted staging sources: 8 x 16B chunks per thread (K: j<4, V: j>=4)
  const bf16_t* gsrc[8];
#pragma unroll
  for (int j = 0; j < 8; ++j) {
    if (j < 4) {
      int u = j * 256 + tid;
      int r = u >> 3, c = u & 7, cs = c ^ (r & 7);
      gsrc[j] = Kbh + r * NHD + cs * 8;
    } else {
      int v = (j - 4) * 256 + tid;
      int r = v >> 4, c = v & 15, cs = (c & 8) | ((c & 7) ^ (r & 7));
      gsrc[j] = Vbh + r * NL + cs * 8;
    }
  }
  auto STAGE = [&](int b) {
#pragma unroll
    for (int j = 0; j < 8; ++j) {
      if (j < 4) {
        async_load16(gsrc[j], &lK[b][(j * 256 + tid) * 8]);
        gsrc[j] += 128 * NHD;
      } else {
        async_load16(gsrc[j], &lV[b][((j - 4) * 256 + tid) * 8]);
        gsrc[j] += 128;
      }
    }
  };

  // hoisted LDS read byte-offsets
  unsigned rdK[2][4], rdV[2][4];
#pragma unroll
  for (int t2 = 0; t2 < 2; ++t2)
#pragma unroll
    for (int c = 0; c < 4; ++c) {
      unsigned un = ((2 * c + hi) ^ (ql & 7)) * 16;
      rdK[t2][c] = (32 * t2 + ql) * 128 + un;
      rdV[t2][c] = (32 * t2 + ql) * 256 + un;
    }
  const char* lKc = (const char*)lK;
  const char* lVc = (const char*)lV;

  STAGE(0);
  int mv0 = mask[bb * NL + lane];
  int mv1 = mask[bb * NL + 64 + lane];
  __syncthreads();

  auto BODY = [&](int buf, int t) {
    int nmv0 = 0, nmv1 = 0;
    if (t < 15) {
      STAGE(buf ^ 1);
      nmv0 = mask[bb * NL + (t + 1) * 128 + lane];
      nmv1 = mask[bb * NL + (t + 1) * 128 + 64 + lane];
    }
    unsigned long long bmA = __ballot(mv0 != 0);
    unsigned long long bmB = __ballot(mv1 != 0);
    unsigned mws[4] = {(unsigned)bmA, (unsigned)(bmA >> 32),
                       (unsigned)bmB, (unsigned)(bmB >> 32)};
    bf16x8 kf5[4];
#pragma unroll
    for (int g = 0; g < 4; ++g) {
      float bv = ((mws[g] >> ql) & 1u) ? -1008.f : -8.f;
      bf16x8 z = {};
      z[0] = (bf16_t)(hi ? 0.f : bv);
      kf5[g] = z;
    }
    // NOTE: no setprio fences in this kernel -- the two hh half-streams are
    // independent until acc; letting the scheduler interleave them is the
    // experiment this round isolates.
#pragma unroll
    for (int hh = 0; hh < 2; ++hh) {
      // ---- S^T = K Q^T + bias: kf5 MFMA first with hoisted zero16 C-in
      f32x16 st[2];
#pragma unroll
      for (int t2 = 0; t2 < 2; ++t2) {
        f32x16 s = __builtin_amdgcn_mfma_f32_32x32x16_bf16(kf5[hh * 2 + t2], qf5,
                                                           zero16, 0, 0, 0);
#pragma unroll
        for (int c = 0; c < 4; ++c) {
          bf16x8 kf = *(const bf16x8*)(lKc + rdK[t2][c] + buf * 16384 + hh * 8192);
          s = __builtin_amdgcn_mfma_f32_32x32x16_bf16(kf, qf[c], s, 0, 0, 0);
        }
        st[t2] = s;
      }

      // ---- p = exp2(s - 8) via raw v_exp_f32; masked -> 2^-1005 = 0
#pragma unroll
      for (int t2 = 0; t2 < 2; ++t2)
#pragma unroll
        for (int r = 0; r < 16; ++r) st[t2][r] = fast_exp2(st[t2][r]);

      // ---- P -> bf16 B-operand fragments via cvt_pk + permlane32_swap
      unsigned wds[2][4][2];
#pragma unroll
      for (int t2 = 0; t2 < 2; ++t2)
#pragma unroll
        for (int r1 = 0; r1 < 4; ++r1) {
          wds[t2][r1][0] = cvtpk_bf16(st[t2][4 * r1 + 0], st[t2][4 * r1 + 1]);
          wds[t2][r1][1] = cvtpk_bf16(st[t2][4 * r1 + 2], st[t2][4 * r1 + 3]);
        }
      bf16x8 pf[4];
#pragma unroll
      for (int kc = 0; kc < 4; ++kc) {
        int t2 = kc >> 1, r1a = 2 * (kc & 1);
        unsigned a0 = wds[t2][r1a][0], b0 = wds[t2][r1a + 1][0];
        unsigned a1 = wds[t2][r1a][1], b1 = wds[t2][r1a + 1][1];
        pl32_swap(a0, b0);
        pl32_swap(a1, b1);
        union { unsigned u[4]; bf16x8 v; } uu;
        uu.u[0] = a0; uu.u[1] = a1; uu.u[2] = b0; uu.u[3] = b1;
        pf[kc] = uu.v;
      }

      // ---- acc^T[d][q] += V^T P^T ; l-partials on the matrix pipe (A = ones)
#pragma unroll
      for (int dt = 0; dt < 2; ++dt) {
        f32x16 a = acc[dt];
#pragma unroll
        for (int kc = 0; kc < 4; ++kc) {
          bf16x8 vf = *(const bf16x8*)(lVc + rdV[dt][kc] + buf * 16384 + hh * 128);
          a = __builtin_amdgcn_mfma_f32_32x32x16_bf16(vf, pf[kc], a, 0, 0, 0);
        }
        acc[dt] = a;
      }
#pragma unroll
      for (int kc = 0; kc < 4; ++kc)
        lacc16 = __builtin_amdgcn_mfma_f32_32x32x16_bf16(ones8, pf[kc], lacc16, 0, 0, 0);
    }
    __syncthreads();
    mv0 = nmv0;
    mv1 = nmv1;
  };

  for (int tt = 0; tt < 8; ++tt) {
    BODY(0, 2 * tt);
    BODY(1, 2 * tt + 1);
  }

  // ---- epilogue: l = lacc16[0] (all rows identical, both lane halves complete)
  float lt = lacc16[0];
  float rinv = lt > 0.f ? 1.f / lt : 0.f;
  const int rowbase = (bb * NL + q) * ND + h * NHD;
#pragma unroll
  for (int dt = 0; dt < 2; ++dt)
#pragma unroll
    for (int r1 = 0; r1 < 4; ++r1) {
      int dbase = 32 * dt + 8 * r1 + 4 * hi;
      bf16x4 g4 = *(const bf16x4*)(Gb + rowbase + dbase);
      bf16x4 o;
#pragma unroll
      for (int j = 0; j < 4; ++j) {
        float gate = 1.f / (1.f + fast_exp2(-1.44269504f * (float)g4[j]));
        o[j] = (bf16_t)(acc[dt][4 * r1 + j] * rinv * gate);
      }
      *(bf16x4*)(X + rowbase + dbase) = o;
    }
}

// ---------------------------------------------------------------- launch
extern "C" void kernel_launch(void* const* d_in, const int* in_sizes, int n_in,
                              void* d_out, int out_size, void* d_ws, size_t ws_size,
                              hipStream_t stream) {
  const float* query = (const float*)d_in[0];
  const float* key   = (const float*)d_in[1];
  const float* value = (const float*)d_in[2];
  const int*   maskp = (const int*)d_in[3];
  const float* rcos  = (const float*)d_in[4];
  const float* rsin  = (const float*)d_in[5];
  const float* Wq = (const float*)d_in[6];  const float* bq = (const float*)d_in[7];
  const float* Wk = (const float*)d_in[8];  const float* bk = (const float*)d_in[9];
  const float* Wv = (const float*)d_in[10]; const float* bv = (const float*)d_in[11];
  const float* Wg = (const float*)d_in[12]; const float* bg = (const float*)d_in[13];
  const float* Wo = (const float*)d_in[14]; const float* bo = (const float*)d_in[15];

  constexpr size_t MB = 1ull << 20;
  char* ws = (char*)d_ws;
  bf16_t* qbb = (bf16_t*)(ws + 0 * MB);
  bf16_t* kbb = (bf16_t*)(ws + 8 * MB);
  bf16_t* vbb = (bf16_t*)(ws + 16 * MB);
  bf16_t* wqb = (bf16_t*)(ws + 24 * MB);
  bf16_t* wkb = (bf16_t*)(ws + 26 * MB);
  bf16_t* wvb = (bf16_t*)(ws + 28 * MB);
  bf16_t* wgb = (bf16_t*)(ws + 30 * MB);
  bf16_t* wob = (bf16_t*)(ws + 32 * MB);
  bf16_t* Qr  = (bf16_t*)(ws + 34 * MB);
  bf16_t* Kr  = (bf16_t*)(ws + 42 * MB);
  bf16_t* Vt  = (bf16_t*)(ws + 50 * MB);
  bf16_t* Gb  = (bf16_t*)(ws + 58 * MB);
  bf16_t* PT  = (bf16_t*)(ws + 66 * MB);   // 512 KB packed rope table
  bf16_t* Xb  = (bf16_t*)(ws + 74 * MB);

  CvtArgs ca;
  ca.s[0] = query; ca.d[0] = qbb;
  ca.s[1] = key;   ca.d[1] = kbb;
  ca.s[2] = value; ca.d[2] = vbb;
  ca.s[3] = Wq;    ca.d[3] = wqb;
  ca.s[4] = Wk;    ca.d[4] = wkb;
  ca.s[5] = Wv;    ca.d[5] = wvb;
  ca.s[6] = Wg;    ca.d[6] = wgb;
  ca.s[7] = Wo;    ca.d[7] = wob;
  ca.rc = rcos; ca.rs = rsin; ca.pt = PT;
  cvt8_kernel<<<dim3(1024, 9), 256, 0, stream>>>(ca);

  gemm8_kernel<<<256, 512, 131072, stream>>>(
      qbb, kbb, vbb, wqb, wkb, wvb, wgb, bq, bk, bv, bg, PT,
      Qr, Kr, Vt, Gb);

  attn_kernel<<<dim3(16, 32), 256, 0, stream>>>(Qr, Kr, Vt, maskp, Gb, Xb);

  gemm_out_kernel<<<256, 256, 0, stream>>>(Xb, wob, bo, (float*)d_out);
}